// Round 6
// baseline (122.111 us; speedup 1.0000x reference)
//
#include <hip/hip_runtime.h>

#define D 64
#define K 1024
#define NPTS 65536
#define OUT_ELEMS (NPTS * D)

typedef _Float16 f16x8 __attribute__((ext_vector_type(8)));
typedef float    f32x4 __attribute__((ext_vector_type(4)));

#define SCL  4096.0f            // 2^12
#define ISCL 0.000244140625f    // 2^-12

// d_ws layout (bytes): eT f32[K][64] @0 (262144) | enorm_half f32[K] @262144
// (4096) | ehf f16 frag-major @266240 (131072) | elf @397312 | end 528384.
//
// Fragment-major layout: for code k, dim d:
//   ct=k>>4, col=k&15, HH=d>>5, r=(d>>3)&3, j=d&7, lane=r*16+col
//   off = ((ct*2+HH)*64 + lane)*8 + j
// Main-loop lane (quad,m) reads its 16B f16x8 B-fragment for tile ct,
// K-half HH at ehf + (ct*2+HH)*512 + lane*8.

// Scaled f16 2-way split: v = h + ls*2^-12. h = RN16(v); ls = RN16((v-h)*2^12)
// is normal-range -> no subnormal-flush hazard; residual ~2^-24|v|.
static __device__ __forceinline__ void split16(float v, _Float16& h, _Float16& ls) {
    h = (_Float16)v;
    const float r = (v - (float)h) * SCL;   // exact scaling (pow2)
    ls = (_Float16)r;
}

// ---------------------------------------------------------------------------
// Prep: tiled transpose emb[D][K] -> eT[K][D] f32 (exact rows for the output
// gather) + fragment-major f16 h/ls arrays + enorm_half[k] = 0.5*||e_k||^2 in
// numpy axis-0 order; zero the loss slot.
// ---------------------------------------------------------------------------
__global__ __launch_bounds__(256) void vq_prep(const float* __restrict__ emb,
                                               float* __restrict__ eT,
                                               float* __restrict__ enorm_h,
                                               _Float16* __restrict__ ehf,
                                               _Float16* __restrict__ elf,
                                               float* __restrict__ loss_out) {
    __shared__ float tile[64][65];
    const int t    = threadIdx.x;
    const int lane = t & 63;
    const int quad = t >> 6;
    const int k0   = blockIdx.x * 64;

#pragma unroll
    for (int i = 0; i < 16; ++i) {
        const int d = i * 4 + quad;
        tile[d][lane] = emb[d * K + k0 + lane];
    }
    __syncthreads();

    const int kk = t >> 2, c = t & 3;
    const int krow = k0 + kk;
    const int ct   = krow >> 4, col = krow & 15;
#pragma unroll
    for (int j = 0; j < 16; ++j) {
        const int d = c * 16 + j;
        const float v = tile[d][kk];
        eT[krow * D + d] = v;
        _Float16 h, ls;
        split16(v, h, ls);
        const int off = ((ct * 2 + (d >> 5)) * 64 + ((d >> 3) & 3) * 16 + col) * 8
                        + (d & 7);
        ehf[off] = h; elf[off] = ls;
    }

    if (t < 64) {   // np add.reduce axis 0: sequential over d
        float s = __fmul_rn(tile[0][t], tile[0][t]);
        for (int dd = 1; dd < D; ++dd)
            s = __fadd_rn(s, __fmul_rn(tile[dd][t], tile[dd][t]));
        enorm_h[k0 + t] = 0.5f * s;
    }
    if (blockIdx.x == 0 && t == 0) *loss_out = 0.0f;
}

static __device__ __forceinline__ float sq8(float a, float b, float c, float d,
                                            float e, float f, float g, float h) {
    float r = __fmul_rn(a, a);
    r = __fadd_rn(r, __fmul_rn(b, b));
    r = __fadd_rn(r, __fmul_rn(c, c));
    r = __fadd_rn(r, __fmul_rn(d, d));
    r = __fadd_rn(r, __fmul_rn(e, e));
    r = __fadd_rn(r, __fmul_rn(f, f));
    r = __fadd_rn(r, __fmul_rn(g, g));
    r = __fadd_rn(r, __fmul_rn(h, h));
    return r;
}

#define PINF(v) asm volatile("" : "+v"(v))

#define MF(A, B, C) __builtin_amdgcn_mfma_f32_16x16x32_f16(A, B, C, 0, 0, 0)

#define MKFRAG16(FH, FS, U0, U1) {                        \
    _Float16 h_, s_;                                      \
    split16(U0.x, h_, s_); FH[0]=h_; FS[0]=s_;            \
    split16(U0.y, h_, s_); FH[1]=h_; FS[1]=s_;            \
    split16(U0.z, h_, s_); FH[2]=h_; FS[2]=s_;            \
    split16(U0.w, h_, s_); FH[3]=h_; FS[3]=s_;            \
    split16(U1.x, h_, s_); FH[4]=h_; FS[4]=s_;            \
    split16(U1.y, h_, s_); FH[5]=h_; FS[5]=s_;            \
    split16(U1.z, h_, s_); FH[6]=h_; FS[6]=s_;            \
    split16(U1.w, h_, s_); FH[7]=h_; FS[7]=s_; }

// ---------------------------------------------------------------------------
// Main (R17): R15 shape (512thr/8 waves, 32pt x 512code per wave, 4 waves/
// SIMD) + software-pipelined ARGMIN (one tile behind MFMA) + enorm folded
// into the MFMA C-in.
// Evidence chain: R13 (no-LDS) = no change; R14 (load prefetch) = -17%;
// R16 (half traffic, half waves) = REGRESSION -> concurrency + per-wave
// dependency structure binds, not operand bandwidth. R15's remaining serial
// element per wave per tile: 12 blocking MFMAs (4-deep c-chain) immediately
// followed by argmin reading the just-written accumulators (full MFMA result
// latency exposed, 4 waves convoy). Fix:
//   (1) two acc sets E/O; body = MFMAs(t) -> B-loads(t+2) -> argmin(t-1):
//       argmin reads accs retired a full tile earlier; waves de-convoy.
//   (2) m-chain C-in = {-enh}: kv = fma(-ISCL, c, -m) (free neg modifier);
//       kills 16 v_sub/tile and removes ENH liveness from the argmin.
// Epilogue (skey/sct stride-33, phase C/D) unchanged from R15.
// Numerics: intra-f32 accumulation-order change only (~1e-7 rel), same
// class as R15's accepted change.
// ---------------------------------------------------------------------------
__global__ __launch_bounds__(512, 4) void vq_main(const float* __restrict__ x,
        const float* __restrict__ eT, const float* __restrict__ enorm_h,
        const _Float16* __restrict__ ehf, const _Float16* __restrict__ elf,
        float* __restrict__ out, float* __restrict__ loss_out) {
    // LDS: rpart 128x8 f32 @0 (4096) | swin 128 i32 @4096 (512) |
    //      skey 128x33 f32 @4608 (16896) | sct 128x33 i32 @21504 (16896) |
    //      end 38400. Stride-33 pad keeps phase-C reads ~conflict-free.
    __shared__ __align__(16) char smem[38400];
    float* rpart = (float*)smem;
    int*   swin  = (int*)(smem + 4096);
    float* skey  = (float*)(smem + 4608);
    int*   sct   = (int*)(smem + 21504);

    const int t     = threadIdx.x;
    const int lane  = t & 63;
    const int w     = t >> 6;          // 0..7
    const int m     = lane & 15;
    const int quad  = lane >> 4;
    const int g     = w >> 1;          // point-group 0..3
    const int h     = w & 1;           // code-half 0..1
    const int pbase = blockIdx.x * 128 + g * 32;

    // ---- Phase A: x -> norm partials + 8 pinned A-frags (2 rowtiles) ----
    f16x8 Ah00, As00, Ah01, As01;   // rowtile 0, K-halves 0/1
    f16x8 Ah10, As10, Ah11, As11;   // rowtile 1
#define LOADA(TT, HH, FH, FS) {                                            \
    const float* px = x + ((size_t)(pbase + TT * 16 + m)) * D + HH * 32 + quad * 8; \
    const float4 u0 = *(const float4*)px;                                  \
    const float4 u1 = *(const float4*)(px + 4);                            \
    if (h == 0)                                                            \
        rpart[(g * 32 + TT * 16 + m) * 8 + (HH * 4 + quad)] =              \
            sq8(u0.x, u0.y, u0.z, u0.w, u1.x, u1.y, u1.z, u1.w);           \
    MKFRAG16(FH, FS, u0, u1); }
    LOADA(0, 0, Ah00, As00)
    LOADA(0, 1, Ah01, As01)
    LOADA(1, 0, Ah10, As10)
    LOADA(1, 1, Ah11, As11)
#undef LOADA
    PINF(Ah00); PINF(As00); PINF(Ah01); PINF(As01);
    PINF(Ah10); PINF(As10); PINF(Ah11); PINF(As11);

    // Persistent zero C-in quad for the correction chains.
    f32x4 ZERO = {0.f, 0.f, 0.f, 0.f};
    PINF(ZERO);

    // ---- Phase B: 32 tiles, MFMA/argmin staggered by one tile ----
    const float FINF = 3.402823466e38f;
    float bk00 = FINF, bk01 = FINF, bk02 = FINF, bk03 = FINF;
    float bk10 = FINF, bk11 = FINF, bk12 = FINF, bk13 = FINF;
    int   bc00 = 0, bc01 = 0, bc02 = 0, bc03 = 0;
    int   bc10 = 0, bc11 = 0, bc12 = 0, bc13 = 0;

    const char* bh = (const char*)ehf + (size_t)h * 65536 + (size_t)lane * 16;
    const char* bs = (const char*)elf + (size_t)h * 65536 + (size_t)lane * 16;
    const float* enp = enorm_h + h * 512 + m;

    // MFMAs for one 16-code tile: m-chain seeded with C-in = -enh (folds the
    // code-norm into the accumulator), c-chain seeded with ZERO.
#define MFMAS(BH0, BH1, BS0, BS1, ENH, M0, M1, C0, C1) {                   \
    const float ne_ = -(ENH);                                              \
    const f32x4 ce_ = {ne_, ne_, ne_, ne_};                                \
    M0 = MF(Ah00, BH0, ce_);   M1 = MF(Ah10, BH0, ce_);                    \
    C0 = MF(As00, BH0, ZERO);  C1 = MF(As10, BH0, ZERO);                   \
    M0 = MF(Ah01, BH1, M0);    M1 = MF(Ah11, BH1, M1);                     \
    C0 = MF(As01, BH1, C0);    C1 = MF(As11, BH1, C1);                     \
    C0 = MF(Ah00, BS0, C0);    C1 = MF(Ah10, BS0, C1);                     \
    C0 = MF(Ah01, BS1, C0);    C1 = MF(Ah11, BS1, C1); }

    // key = enh - hh - ISCL*corr = -(m_acc) - ISCL*c  (neg modifier free)
#define AC1(BK, BC, MV, CV, CT) {                                          \
    const float kv = __builtin_fmaf(-ISCL, CV, -(MV));                     \
    if (kv < BK) { BK = kv; BC = (CT); } }

#define ARGM(M0, M1, C0, C1, CT) {                                         \
    AC1(bk00, bc00, M0[0], C0[0], CT)  AC1(bk01, bc01, M0[1], C0[1], CT)   \
    AC1(bk02, bc02, M0[2], C0[2], CT)  AC1(bk03, bc03, M0[3], C0[3], CT)   \
    AC1(bk10, bc10, M1[0], C1[0], CT)  AC1(bk11, bc11, M1[1], C1[1], CT)   \
    AC1(bk12, bc12, M1[2], C1[2], CT)  AC1(bk13, bc13, M1[3], C1[3], CT) }

#define LOADB(TT, BH0, BH1, BS0, BS1, ENH) {                               \
    const int ob_ = (TT) * 2048;                                           \
    BH0 = *(const f16x8*)(bh + ob_);        BH1 = *(const f16x8*)(bh + ob_ + 1024); \
    BS0 = *(const f16x8*)(bs + ob_);        BS1 = *(const f16x8*)(bs + ob_ + 1024); \
    ENH = enp[(TT) * 16]; }

    f16x8 aBh0, aBh1, aBs0, aBs1;  float aEn;   // buffer A (even tiles)
    f16x8 pBh0, pBh1, pBs0, pBs1;  float pEn;   // buffer B (odd tiles)
    f32x4 mE0, mE1, cE0, cE1;                   // acc set E (even tiles)
    f32x4 mO0, mO1, cO0, cO1;                   // acc set O (odd tiles)

    LOADB(0, aBh0, aBh1, aBs0, aBs1, aEn)       // tile 0 -> A
    LOADB(1, pBh0, pBh1, pBs0, pBs1, pEn)       // tile 1 -> B
    MFMAS(aBh0, aBh1, aBs0, aBs1, aEn, mE0, mE1, cE0, cE1)   // tile 0
    LOADB(2, aBh0, aBh1, aBs0, aBs1, aEn)       // tile 2 -> A

    for (int j = 0; j < 15; ++j) {
        const int t1 = 2 * j + 1;
        const int t2 = 2 * j + 2;
        const int t3 = 2 * j + 3;
        const int t4 = (2 * j + 4) & 31;        // wrap: harmless re-read
        MFMAS(pBh0, pBh1, pBs0, pBs1, pEn, mO0, mO1, cO0, cO1)   // tile t1
        LOADB(t3, pBh0, pBh1, pBs0, pBs1, pEn)
        ARGM(mE0, mE1, cE0, cE1, 2 * j)                          // tile 2j
        MFMAS(aBh0, aBh1, aBs0, aBs1, aEn, mE0, mE1, cE0, cE1)   // tile t2
        LOADB(t4, aBh0, aBh1, aBs0, aBs1, aEn)
        ARGM(mO0, mO1, cO0, cO1, t1)                             // tile t1
    }
    MFMAS(pBh0, pBh1, pBs0, pBs1, pEn, mO0, mO1, cO0, cO1)       // tile 31
    ARGM(mE0, mE1, cE0, cE1, 30)
    ARGM(mO0, mO1, cO0, cO1, 31)
#undef LOADB
#undef ARGM
#undef AC1
#undef MFMAS

    // C-layout: row = quad*4 + reg, col = m; class = h*16 + m (32 classes).
#define PUTC(TT, REG, BK, BC) {                                   \
    const int ploc = g * 32 + TT * 16 + quad * 4 + REG;           \
    skey[ploc * 33 + h * 16 + m] = BK;                            \
    sct [ploc * 33 + h * 16 + m] = BC; }
    PUTC(0, 0, bk00, bc00) PUTC(0, 1, bk01, bc01)
    PUTC(0, 2, bk02, bc02) PUTC(0, 3, bk03, bc03)
    PUTC(1, 0, bk10, bc10) PUTC(1, 1, bk11, bc11)
    PUTC(1, 2, bk12, bc12) PUTC(1, 3, bk13, bc13)
#undef PUTC
    __syncthreads();

    // ---- Phase C (t<128): lex (key, idx) combine over 32 classes ----
    if (t < 128) {
        const int p = t;
        const float* rp = rpart + p * 8;
        const float A = ((rp[0] + rp[1]) + (rp[2] + rp[3])) +
                        ((rp[4] + rp[5]) + (rp[6] + rp[7]));
        float fb = FINF;
        int   fi = 0;
#pragma unroll
        for (int c = 0; c < 32; ++c) {
            const float kv = skey[p * 33 + c];
            const int   iv = (c >> 4) * 512 + sct[p * 33 + c] * 16 + (c & 15);
            if (kv < fb || (kv == fb && iv < fi)) { fb = kv; fi = iv; }
        }
        swin[p] = fi;
        float lp = fmaf(2.0f, fb, A);   // ||x-q||^2 = A + 2*key
#pragma unroll
        for (int off = 32; off > 0; off >>= 1) lp += __shfl_down(lp, off, 64);
        if (lane == 0) atomicAdd(loss_out, lp * (1.25f / (float)OUT_ELEMS));
    }
    __syncthreads();

    // ---- Phase D: direct coalesced gather-write. 16 consecutive lanes
    // write the 16 float4 chunks of one point; eT row read is 256 B
    // contiguous from L2-resident eT. Bit-exact row copy. ----
    {
        const float4* eT4 = (const float4*)eT;
        float4* og = (float4*)out + (size_t)blockIdx.x * 2048;
#pragma unroll
        for (int s = 0; s < 4; ++s) {
            const int f  = s * 512 + t;          // 0..2047 float4s
            const int fi = swin[f >> 4];
            og[f] = eT4[(size_t)fi * 16 + (f & 15)];
        }
    }
}

extern "C" void kernel_launch(void* const* d_in, const int* in_sizes, int n_in,
                              void* d_out, int out_size, void* d_ws, size_t ws_size,
                              hipStream_t stream) {
    const float* x   = (const float*)d_in[0];   // [64,32,32,64] fp32
    const float* emb = (const float*)d_in[1];   // [64,1024] fp32
    float* out       = (float*)d_out;           // [quantized | loss]
    char*  ws        = (char*)d_ws;             // needs 528384 B
    float*    eT      = (float*)ws;
    float*    enorm_h = (float*)(ws + 262144);
    _Float16* ehf     = (_Float16*)(ws + 266240);
    _Float16* elf     = (_Float16*)(ws + 397312);
    float* loss_out   = out + OUT_ELEMS;

    vq_prep<<<dim3(K / 64), dim3(256), 0, stream>>>(emb, eT, enorm_h, ehf, elf,
                                                    loss_out);
    vq_main<<<dim3(NPTS / 128), dim3(512), 0, stream>>>(x, eT, enorm_h, ehf,
                                                        elf, out, loss_out);
}